// Round 3
// baseline (114.716 us; speedup 1.0000x reference)
//
#include <hip/hip_runtime.h>
#include <math.h>

#define S_GRID   112
#define BATCH_N  64
#define NBOX     100
#define NCELLS   (BATCH_N * S_GRID * S_GRID)   // 802816
#define CELLSZ   (1.0f / (float)S_GRID)
#define BLK      256
#define NBLK2    (NCELLS / BLK)                // 3136 exactly
#define ZERO_U4  ((NCELLS * 12) / 16 + 1)      // keybuf+clsmask+counter pad = 602113 uint4
#define NBLKZ    ((ZERO_U4 + BLK - 1) / BLK)

// ---------- device helpers ----------

__device__ __forceinline__ float iou_fn(float px, float py, float pw, float ph,
                                        float gx, float gy, float gw, float gh) {
    // matches reference _iou (eps = 1e-6)
    float px1 = px - pw * 0.5f, px2 = px + pw * 0.5f;
    float py1 = py - ph * 0.5f, py2 = py + ph * 0.5f;
    float gx1 = gx - gw * 0.5f, gx2 = gx + gw * 0.5f;
    float gy1 = gy - gh * 0.5f, gy2 = gy + gh * 0.5f;
    float iw = fmaxf(fminf(px2, gx2) - fmaxf(px1, gx1), 0.f);
    float ih = fmaxf(fminf(py2, gy2) - fmaxf(py1, gy1), 0.f);
    float inter = iw * ih;
    float ap = fmaxf(px2 - px1, 0.f) * fmaxf(py2 - py1, 0.f);
    float ag = fmaxf(gx2 - gx1, 0.f) * fmaxf(gy2 - gy1, 0.f);
    float uni = ap + ag - inter;
    return inter / (uni + 1e-6f);
}

__device__ __forceinline__ float ciou_fn(float px, float py, float pw, float ph,
                                         float gx, float gy, float gw, float gh) {
    // matches reference _ciou (eps = 1e-7)
    const float eps = 1e-7f;
    float px1 = px - pw * 0.5f, px2 = px + pw * 0.5f;
    float py1 = py - ph * 0.5f, py2 = py + ph * 0.5f;
    float gx1 = gx - gw * 0.5f, gx2 = gx + gw * 0.5f;
    float gy1 = gy - gh * 0.5f, gy2 = gy + gh * 0.5f;
    float iw = fmaxf(fminf(px2, gx2) - fmaxf(px1, gx1), 0.f);
    float ih = fmaxf(fminf(py2, gy2) - fmaxf(py1, gy1), 0.f);
    float inter = iw * ih;
    float ap = fmaxf(px2 - px1, 0.f) * fmaxf(py2 - py1, 0.f);
    float ag = fmaxf(gx2 - gx1, 0.f) * fmaxf(gy2 - gy1, 0.f);
    float uni = ap + ag - inter;
    float iou = inter / (uni + eps);
    float dx = px - gx, dy = py - gy;
    float rho2 = dx * dx + dy * dy;
    float cw = fmaxf(px2, gx2) - fminf(px1, gx1);
    float ch = fmaxf(py2, gy2) - fminf(py1, gy1);
    float c2 = cw * cw + ch * ch + eps;
    float dv = atanf(gw / (gh + eps)) - atanf(pw / (ph + eps));
    float v = 0.40528473456935109f * dv * dv;   // 4/pi^2
    float alpha = v / (1.f - iou + v + eps);
    return 1.f - iou + rho2 / c2 + alpha * v;
}

__device__ __forceinline__ float focal_fn(float logit, float t) {
    float bce = fmaxf(logit, 0.f) - logit * t + log1pf(expf(-fabsf(logit)));
    float p = 1.f / (1.f + expf(-logit));
    float p_t = t * p + (1.f - t) * (1.f - p);
    float a_t = t * 0.25f + (1.f - t) * 0.75f;
    float om = 1.f - p_t;
    return a_t * om * om * bce;
}

// ---------- kernel 0: workspace zero (keybuf + clsmask + done-counter) ----------

__global__ void zero_kernel(uint4* __restrict__ ws) {
    int i = blockIdx.x * blockDim.x + threadIdx.x;
    if (i < ZERO_U4) ws[i] = make_uint4(0u, 0u, 0u, 0u);
}

// ---------- kernel 1: per-box assignment via atomics ----------

__global__ void assign_kernel(const float* __restrict__ pred,
                              const float* __restrict__ tgt,
                              unsigned long long* __restrict__ keybuf,
                              unsigned int* __restrict__ clsmask) {
    int m = blockIdx.x * blockDim.x + threadIdx.x;
    if (m >= BATCH_N * NBOX) return;
    const float* t = tgt + (size_t)m * 5;
    float t0 = t[0];
    if (t0 < 0.f) return;                       // invalid box
    int cls = (int)t0; cls = min(max(cls, 0), 9);
    float cx = t[1], cy = t[2], gw = t[3], gh = t[4];
    int b = m / NBOX;
    int col = min(max((int)(cx * (float)S_GRID), 0), S_GRID - 1);
    int row = min(max((int)(cy * (float)S_GRID), 0), S_GRID - 1);
    const float* p = pred + ((((size_t)b * S_GRID + row) * S_GRID) + col) * 20;
    float dx0 = (p[0] + (float)col) * CELLSZ, dy0 = (p[1] + (float)row) * CELLSZ;
    float iou0 = iou_fn(dx0, dy0, p[2], p[3], cx, cy, gw, gh);
    float dx1 = (p[5] + (float)col) * CELLSZ, dy1 = (p[6] + (float)row) * CELLSZ;
    float iou1 = iou_fn(dx1, dy1, p[7], p[8], cx, cy, gw, gh);
    float best = fmaxf(iou0, iou1);             // iou >= 0 -> bits monotone as uint
    int cid = ((b * S_GRID) + row) * S_GRID + col;
    unsigned long long key =
        ((unsigned long long)__float_as_uint(best) << 32) |
        (unsigned long long)(0xFFFFFFFFu - (unsigned)m);   // tie-break: smallest m wins
    atomicMax(&keybuf[cid], key);
    atomicOr(&clsmask[cid], 1u << cls);
}

// ---------- kernel 2: per-cell loss + fused final reduction (last block) ----------

__global__ void loss_kernel(const float* __restrict__ pred,
                            const float* __restrict__ tgt,
                            const unsigned long long* __restrict__ keybuf,
                            const unsigned int* __restrict__ clsmask,
                            float* __restrict__ partial,
                            unsigned int* __restrict__ done_ctr,
                            float* __restrict__ out) {
    int cid = blockIdx.x * blockDim.x + threadIdx.x;   // grid covers NCELLS exactly
    float acc = 0.f;

    const float4* p4 = (const float4*)(pred + (size_t)cid * 20);
    float4 a = p4[0];   // px0 py0 pw0 ph0
    float4 bq = p4[1];  // conf0 px1 py1 pw1
    float4 c = p4[2];   // ph1 conf1 cls0 cls1
    float4 d = p4[3];   // cls2..cls5
    float4 e = p4[4];   // cls6..cls9
    float conf0 = bq.x, conf1 = c.y;

    unsigned int mask = clsmask[cid];
    if (mask == 0u) {
        acc = 0.1f * (conf0 * conf0 + conf1 * conf1);
    } else {
        int rc  = cid % (S_GRID * S_GRID);
        float colf = (float)(rc % S_GRID);
        float rowf = (float)(rc / S_GRID);

        unsigned long long key = keybuf[cid];
        int m = (int)(0xFFFFFFFFu - (unsigned)(key & 0xFFFFFFFFull));
        float best_iou = __uint_as_float((unsigned)(key >> 32));
        const float* t = tgt + (size_t)m * 5;
        float cx = t[1], cy = t[2], gw = t[3], gh = t[4];

        // recompute best_j exactly as kernel 1 did
        float dx0 = (a.x + colf) * CELLSZ, dy0 = (a.y + rowf) * CELLSZ;
        float iou0 = iou_fn(dx0, dy0, a.z, a.w, cx, cy, gw, gh);
        float dx1 = (bq.y + colf) * CELLSZ, dy1 = (bq.z + rowf) * CELLSZ;
        float iou1 = iou_fn(dx1, dy1, bq.w, c.x, cx, cy, gw, gh);
        int bj = (iou0 >= iou1) ? 0 : 1;        // argmax, first max wins

        float rx = bj ? bq.y : a.x;
        float ry = bj ? bq.z : a.y;
        float rw = bj ? bq.w : a.z;
        float rh = bj ? c.x  : a.w;
        float rconf = bj ? c.y : bq.x;
        float oconf = bj ? bq.x : c.y;

        float pax = (rx + colf) * CELLSZ, pay = (ry + rowf) * CELLSZ;
        float paw = fabsf(rw), pah = fabsf(rh);
        float cx_rel = cx * (float)S_GRID - colf;
        float cy_rel = cy * (float)S_GRID - rowf;
        float gax = (cx_rel + colf) * CELLSZ;
        float gay = (cy_rel + rowf) * CELLSZ;
        float lcoord = ciou_fn(pax, pay, paw, pah, gax, gay, gw, gh);

        float dobj = rconf - best_iou;

        float cls_logit[10];
        cls_logit[0] = c.z; cls_logit[1] = c.w;
        cls_logit[2] = d.x; cls_logit[3] = d.y; cls_logit[4] = d.z; cls_logit[5] = d.w;
        cls_logit[6] = e.x; cls_logit[7] = e.y; cls_logit[8] = e.z; cls_logit[9] = e.w;
        float lcls = 0.f;
#pragma unroll
        for (int k = 0; k < 10; ++k) {
            float tk = (mask >> k) & 1u ? 1.f : 0.f;
            lcls += focal_fn(cls_logit[k], tk);
        }

        acc = 5.f * lcoord + dobj * dobj + 0.1f * (oconf * oconf) + lcls;
    }

    // deterministic block reduction: wave64 shuffle + LDS across 4 waves
    for (int off = 32; off > 0; off >>= 1) acc += __shfl_down(acc, off);
    __shared__ float sred[BLK / 64];
    int lane = threadIdx.x & 63, wid = threadIdx.x >> 6;
    if (lane == 0) sred[wid] = acc;
    __syncthreads();
    __shared__ bool amlast;
    if (threadIdx.x == 0) {
        float s = 0.f;
#pragma unroll
        for (int w = 0; w < BLK / 64; ++w) s += sred[w];
        partial[blockIdx.x] = s;
        __threadfence();                                   // release partial[]
        unsigned int old = atomicAdd(done_ctr, 1u);        // device-scope
        amlast = (old == NBLK2 - 1);
    }
    __syncthreads();
    if (!amlast) return;

    // last block: deterministic fixed-order sum of all partials
    __threadfence();
    float facc = 0.f;
    for (int i = threadIdx.x; i < NBLK2; i += BLK) {
        unsigned int bits = __hip_atomic_load((const unsigned int*)&partial[i],
                                              __ATOMIC_RELAXED, __HIP_MEMORY_SCOPE_AGENT);
        facc += __uint_as_float(bits);
    }
    for (int off = 32; off > 0; off >>= 1) facc += __shfl_down(facc, off);
    if (lane == 0) sred[wid] = facc;
    __syncthreads();
    if (threadIdx.x == 0) {
        float s = 0.f;
#pragma unroll
        for (int w = 0; w < BLK / 64; ++w) s += sred[w];
        out[0] = s / (float)BATCH_N;
    }
}

// ---------- launcher ----------

extern "C" void kernel_launch(void* const* d_in, const int* in_sizes, int n_in,
                              void* d_out, int out_size, void* d_ws, size_t ws_size,
                              hipStream_t stream) {
    const float* pred = (const float*)d_in[0];
    const float* tgt  = (const float*)d_in[1];

    // workspace layout (16B-aligned chunks)
    unsigned long long* keybuf   = (unsigned long long*)d_ws;               // 8B * NCELLS
    unsigned int*       clsmask  = (unsigned int*)(keybuf + NCELLS);        // 4B * NCELLS
    unsigned int*       done_ctr = (unsigned int*)(clsmask + NCELLS);       // 16B slot
    float*              partial  = (float*)((char*)done_ctr + 16);          // 4B * NBLK2

    zero_kernel<<<NBLKZ, BLK, 0, stream>>>((uint4*)d_ws);

    assign_kernel<<<(BATCH_N * NBOX + BLK - 1) / BLK, BLK, 0, stream>>>(
        pred, tgt, keybuf, clsmask);
    loss_kernel<<<NBLK2, BLK, 0, stream>>>(pred, tgt, keybuf, clsmask,
                                           partial, done_ctr, (float*)d_out);
}

// Round 4
// 51.008 us; speedup vs baseline: 2.2490x; 2.2490x over previous
//
#include <hip/hip_runtime.h>
#include <math.h>

#define S_GRID   112
#define BATCH_N  64
#define NBOX     100
#define NCELLS   (BATCH_N * S_GRID * S_GRID)   // 802816
#define CELLSZ   (1.0f / (float)S_GRID)
#define BLK      256
#define NBLK2    (NCELLS / BLK)                // 3136 exactly
#define ZERO_U4  ((NCELLS * 12) / 16)          // 602112 uint4s, exact
#define NBLKZ    (ZERO_U4 / BLK)               // 2352 exactly
#define PSTRIDE  21                            // 20 floats + 1 pad: gcd(21,32)=1 -> conflict-free

// ---------- device helpers ----------

__device__ __forceinline__ float iou_fn(float px, float py, float pw, float ph,
                                        float gx, float gy, float gw, float gh) {
    // matches reference _iou (eps = 1e-6)
    float px1 = px - pw * 0.5f, px2 = px + pw * 0.5f;
    float py1 = py - ph * 0.5f, py2 = py + ph * 0.5f;
    float gx1 = gx - gw * 0.5f, gx2 = gx + gw * 0.5f;
    float gy1 = gy - gh * 0.5f, gy2 = gy + gh * 0.5f;
    float iw = fmaxf(fminf(px2, gx2) - fmaxf(px1, gx1), 0.f);
    float ih = fmaxf(fminf(py2, gy2) - fmaxf(py1, gy1), 0.f);
    float inter = iw * ih;
    float ap = fmaxf(px2 - px1, 0.f) * fmaxf(py2 - py1, 0.f);
    float ag = fmaxf(gx2 - gx1, 0.f) * fmaxf(gy2 - gy1, 0.f);
    float uni = ap + ag - inter;
    return inter / (uni + 1e-6f);
}

__device__ __forceinline__ float ciou_fn(float px, float py, float pw, float ph,
                                         float gx, float gy, float gw, float gh) {
    // matches reference _ciou (eps = 1e-7)
    const float eps = 1e-7f;
    float px1 = px - pw * 0.5f, px2 = px + pw * 0.5f;
    float py1 = py - ph * 0.5f, py2 = py + ph * 0.5f;
    float gx1 = gx - gw * 0.5f, gx2 = gx + gw * 0.5f;
    float gy1 = gy - gh * 0.5f, gy2 = gy + gh * 0.5f;
    float iw = fmaxf(fminf(px2, gx2) - fmaxf(px1, gx1), 0.f);
    float ih = fmaxf(fminf(py2, gy2) - fmaxf(py1, gy1), 0.f);
    float inter = iw * ih;
    float ap = fmaxf(px2 - px1, 0.f) * fmaxf(py2 - py1, 0.f);
    float ag = fmaxf(gx2 - gx1, 0.f) * fmaxf(gy2 - gy1, 0.f);
    float uni = ap + ag - inter;
    float iou = inter / (uni + eps);
    float dx = px - gx, dy = py - gy;
    float rho2 = dx * dx + dy * dy;
    float cw = fmaxf(px2, gx2) - fminf(px1, gx1);
    float ch = fmaxf(py2, gy2) - fminf(py1, gy1);
    float c2 = cw * cw + ch * ch + eps;
    float dv = atanf(gw / (gh + eps)) - atanf(pw / (ph + eps));
    float v = 0.40528473456935109f * dv * dv;   // 4/pi^2
    float alpha = v / (1.f - iou + v + eps);
    return 1.f - iou + rho2 / c2 + alpha * v;
}

__device__ __forceinline__ float focal_fn(float logit, float t) {
    float bce = fmaxf(logit, 0.f) - logit * t + log1pf(expf(-fabsf(logit)));
    float p = 1.f / (1.f + expf(-logit));
    float p_t = t * p + (1.f - t) * (1.f - p);
    float a_t = t * 0.25f + (1.f - t) * 0.75f;
    float om = 1.f - p_t;
    return a_t * om * om * bce;
}

// ---------- kernel 0: workspace zero ----------

__global__ void zero_kernel(uint4* __restrict__ ws) {
    int i = blockIdx.x * blockDim.x + threadIdx.x;   // grid covers ZERO_U4 exactly
    ws[i] = make_uint4(0u, 0u, 0u, 0u);
}

// ---------- kernel 1: per-box assignment via atomics ----------

__global__ void assign_kernel(const float* __restrict__ pred,
                              const float* __restrict__ tgt,
                              unsigned long long* __restrict__ keybuf,
                              unsigned int* __restrict__ clsmask) {
    int m = blockIdx.x * blockDim.x + threadIdx.x;
    if (m >= BATCH_N * NBOX) return;
    const float* t = tgt + (size_t)m * 5;
    float t0 = t[0];
    if (t0 < 0.f) return;                       // invalid box
    int cls = (int)t0; cls = min(max(cls, 0), 9);
    float cx = t[1], cy = t[2], gw = t[3], gh = t[4];
    int b = m / NBOX;
    int col = min(max((int)(cx * (float)S_GRID), 0), S_GRID - 1);
    int row = min(max((int)(cy * (float)S_GRID), 0), S_GRID - 1);
    const float* p = pred + ((((size_t)b * S_GRID + row) * S_GRID) + col) * 20;
    float dx0 = (p[0] + (float)col) * CELLSZ, dy0 = (p[1] + (float)row) * CELLSZ;
    float iou0 = iou_fn(dx0, dy0, p[2], p[3], cx, cy, gw, gh);
    float dx1 = (p[5] + (float)col) * CELLSZ, dy1 = (p[6] + (float)row) * CELLSZ;
    float iou1 = iou_fn(dx1, dy1, p[7], p[8], cx, cy, gw, gh);
    float best = fmaxf(iou0, iou1);             // iou >= 0 -> bits monotone as uint
    int cid = ((b * S_GRID) + row) * S_GRID + col;
    unsigned long long key =
        ((unsigned long long)__float_as_uint(best) << 32) |
        (unsigned long long)(0xFFFFFFFFu - (unsigned)m);   // tie-break: smallest m wins
    atomicMax(&keybuf[cid], key);
    atomicOr(&clsmask[cid], 1u << cls);
}

// ---------- kernel 2: per-cell loss (LDS-staged pred reads) ----------

__global__ void loss_kernel(const float* __restrict__ pred,
                            const float* __restrict__ tgt,
                            const unsigned long long* __restrict__ keybuf,
                            const unsigned int* __restrict__ clsmask,
                            float* __restrict__ partial) {
    __shared__ float sp[BLK * PSTRIDE];   // 21504 B -> 7 blocks/CU
    int cid = blockIdx.x * blockDim.x + threadIdx.x;   // grid covers NCELLS exactly

    // coalesced staging: 1280 float4s, lane-contiguous; scatter to padded LDS rows
    const float4* src = (const float4*)(pred + (size_t)blockIdx.x * BLK * 20);
#pragma unroll
    for (int k = 0; k < 5; ++k) {
        int i = threadIdx.x + k * BLK;    // 0..1279
        float4 v = src[i];
        float* dst = &sp[(i / 5) * PSTRIDE + (i % 5) * 4];
        dst[0] = v.x; dst[1] = v.y; dst[2] = v.z; dst[3] = v.w;
    }
    __syncthreads();

    const float* P = &sp[threadIdx.x * PSTRIDE];
    float conf0 = P[4], conf1 = P[9];
    float acc = 0.f;

    unsigned int mask = clsmask[cid];
    if (mask == 0u) {
        acc = 0.1f * (conf0 * conf0 + conf1 * conf1);
    } else {
        int rc  = cid % (S_GRID * S_GRID);
        float colf = (float)(rc % S_GRID);
        float rowf = (float)(rc / S_GRID);

        unsigned long long key = keybuf[cid];
        int m = (int)(0xFFFFFFFFu - (unsigned)(key & 0xFFFFFFFFull));
        float best_iou = __uint_as_float((unsigned)(key >> 32));
        const float* t = tgt + (size_t)m * 5;
        float cx = t[1], cy = t[2], gw = t[3], gh = t[4];

        // recompute best_j exactly as kernel 1 did
        float dx0 = (P[0] + colf) * CELLSZ, dy0 = (P[1] + rowf) * CELLSZ;
        float iou0 = iou_fn(dx0, dy0, P[2], P[3], cx, cy, gw, gh);
        float dx1 = (P[5] + colf) * CELLSZ, dy1 = (P[6] + rowf) * CELLSZ;
        float iou1 = iou_fn(dx1, dy1, P[7], P[8], cx, cy, gw, gh);
        int bj = (iou0 >= iou1) ? 0 : 1;        // argmax, first max wins

        float rx = bj ? P[5] : P[0];
        float ry = bj ? P[6] : P[1];
        float rw = bj ? P[7] : P[2];
        float rh = bj ? P[8] : P[3];
        float rconf = bj ? conf1 : conf0;
        float oconf = bj ? conf0 : conf1;

        float pax = (rx + colf) * CELLSZ, pay = (ry + rowf) * CELLSZ;
        float paw = fabsf(rw), pah = fabsf(rh);
        float cx_rel = cx * (float)S_GRID - colf;
        float cy_rel = cy * (float)S_GRID - rowf;
        float gax = (cx_rel + colf) * CELLSZ;
        float gay = (cy_rel + rowf) * CELLSZ;
        float lcoord = ciou_fn(pax, pay, paw, pah, gax, gay, gw, gh);

        float dobj = rconf - best_iou;

        float lcls = 0.f;
#pragma unroll
        for (int k = 0; k < 10; ++k) {
            float tk = (mask >> k) & 1u ? 1.f : 0.f;
            lcls += focal_fn(P[10 + k], tk);
        }

        acc = 5.f * lcoord + dobj * dobj + 0.1f * (oconf * oconf) + lcls;
    }

    // deterministic block reduction: wave64 shuffle + LDS across 4 waves
    for (int off = 32; off > 0; off >>= 1) acc += __shfl_down(acc, off);
    __shared__ float sred[BLK / 64];
    int lane = threadIdx.x & 63, wid = threadIdx.x >> 6;
    if (lane == 0) sred[wid] = acc;
    __syncthreads();
    if (threadIdx.x == 0) {
        float s = 0.f;
#pragma unroll
        for (int w = 0; w < BLK / 64; ++w) s += sred[w];
        partial[blockIdx.x] = s;
    }
}

// ---------- kernel 3: final reduction ----------

__global__ void reduce_kernel(const float* __restrict__ partial, float* __restrict__ out) {
    float acc = 0.f;
    for (int i = threadIdx.x; i < NBLK2; i += blockDim.x) acc += partial[i];
    for (int off = 32; off > 0; off >>= 1) acc += __shfl_down(acc, off);
    __shared__ float sred[BLK / 64];
    int lane = threadIdx.x & 63, wid = threadIdx.x >> 6;
    if (lane == 0) sred[wid] = acc;
    __syncthreads();
    if (threadIdx.x == 0) {
        float s = 0.f;
#pragma unroll
        for (int w = 0; w < BLK / 64; ++w) s += sred[w];
        out[0] = s / (float)BATCH_N;
    }
}

// ---------- launcher ----------

extern "C" void kernel_launch(void* const* d_in, const int* in_sizes, int n_in,
                              void* d_out, int out_size, void* d_ws, size_t ws_size,
                              hipStream_t stream) {
    const float* pred = (const float*)d_in[0];
    const float* tgt  = (const float*)d_in[1];

    // workspace layout
    unsigned long long* keybuf  = (unsigned long long*)d_ws;                 // 8B * NCELLS
    unsigned int*       clsmask = (unsigned int*)(keybuf + NCELLS);          // 4B * NCELLS
    float*              partial = (float*)(clsmask + NCELLS);                // 4B * NBLK2

    zero_kernel<<<NBLKZ, BLK, 0, stream>>>((uint4*)d_ws);

    assign_kernel<<<(BATCH_N * NBOX + BLK - 1) / BLK, BLK, 0, stream>>>(
        pred, tgt, keybuf, clsmask);
    loss_kernel<<<NBLK2, BLK, 0, stream>>>(pred, tgt, keybuf, clsmask, partial);
    reduce_kernel<<<1, BLK, 0, stream>>>(partial, (float*)d_out);
}

// Round 5
// 50.475 us; speedup vs baseline: 2.2727x; 1.0106x over previous
//
#include <hip/hip_runtime.h>
#include <math.h>

#define S_GRID   112
#define BATCH_N  64
#define NBOX     100
#define SS       (S_GRID * S_GRID)       // 12544 cells per image
#define NCELLS   (BATCH_N * SS)          // 802816
#define CELLSZ   (1.0f / (float)S_GRID)
#define BLK      256
#define BLKS_PER_IMG (SS / BLK)          // 49 exactly
#define NBLK     (NCELLS / BLK)          // 3136
#define PSTRIDE  21                      // 20 floats + 1 pad (gcd(21,32)=1, conflict-free)
#define HITW     (SS / 32)               // 392 words of hit bitmap

// ---------- device helpers ----------

__device__ __forceinline__ float iou_fn(float px, float py, float pw, float ph,
                                        float gx, float gy, float gw, float gh) {
    // matches reference _iou (eps = 1e-6)
    float px1 = px - pw * 0.5f, px2 = px + pw * 0.5f;
    float py1 = py - ph * 0.5f, py2 = py + ph * 0.5f;
    float gx1 = gx - gw * 0.5f, gx2 = gx + gw * 0.5f;
    float gy1 = gy - gh * 0.5f, gy2 = gy + gh * 0.5f;
    float iw = fmaxf(fminf(px2, gx2) - fmaxf(px1, gx1), 0.f);
    float ih = fmaxf(fminf(py2, gy2) - fmaxf(py1, gy1), 0.f);
    float inter = iw * ih;
    float ap = fmaxf(px2 - px1, 0.f) * fmaxf(py2 - py1, 0.f);
    float ag = fmaxf(gx2 - gx1, 0.f) * fmaxf(gy2 - gy1, 0.f);
    float uni = ap + ag - inter;
    return inter / (uni + 1e-6f);
}

__device__ __forceinline__ float ciou_fn(float px, float py, float pw, float ph,
                                         float gx, float gy, float gw, float gh) {
    // matches reference _ciou (eps = 1e-7)
    const float eps = 1e-7f;
    float px1 = px - pw * 0.5f, px2 = px + pw * 0.5f;
    float py1 = py - ph * 0.5f, py2 = py + ph * 0.5f;
    float gx1 = gx - gw * 0.5f, gx2 = gx + gw * 0.5f;
    float gy1 = gy - gh * 0.5f, gy2 = gy + gh * 0.5f;
    float iw = fmaxf(fminf(px2, gx2) - fmaxf(px1, gx1), 0.f);
    float ih = fmaxf(fminf(py2, gy2) - fmaxf(py1, gy1), 0.f);
    float inter = iw * ih;
    float ap = fmaxf(px2 - px1, 0.f) * fmaxf(py2 - py1, 0.f);
    float ag = fmaxf(gx2 - gx1, 0.f) * fmaxf(gy2 - gy1, 0.f);
    float uni = ap + ag - inter;
    float iou = inter / (uni + eps);
    float dx = px - gx, dy = py - gy;
    float rho2 = dx * dx + dy * dy;
    float cw = fmaxf(px2, gx2) - fminf(px1, gx1);
    float ch = fmaxf(py2, gy2) - fminf(py1, gy1);
    float c2 = cw * cw + ch * ch + eps;
    float dv = atanf(gw / (gh + eps)) - atanf(pw / (ph + eps));
    float v = 0.40528473456935109f * dv * dv;   // 4/pi^2
    float alpha = v / (1.f - iou + v + eps);
    return 1.f - iou + rho2 / c2 + alpha * v;
}

__device__ __forceinline__ float focal_fn(float logit, float t) {
    float bce = fmaxf(logit, 0.f) - logit * t + log1pf(expf(-fabsf(logit)));
    float p = 1.f / (1.f + expf(-logit));
    float p_t = t * p + (1.f - t) * (1.f - p);
    float a_t = t * 0.25f + (1.f - t) * 0.75f;
    float om = 1.f - p_t;
    return a_t * om * om * bce;
}

// ---------- kernel 1: self-contained per-cell loss ----------
// Each block owns 256 cells of ONE image (49 blocks/image). The image's 100
// targets are tabled in LDS; each thread resolves its cell's winner locally.
// No global workspace state, no atomics, no zeroing pass.

__global__ __launch_bounds__(BLK) void loss_kernel(const float* __restrict__ pred,
                                                   const float* __restrict__ tgt,
                                                   float* __restrict__ partial) {
    __shared__ float    sp[BLK * PSTRIDE];   // staged preds, padded rows
    __shared__ int      s_cell[NBOX];        // image-local cell id per box (-1 invalid)
    __shared__ float4   s_box[NBOX];         // cx, cy, w, h
    __shared__ unsigned s_cbit[NBOX];        // class bit
    __shared__ unsigned s_hit[HITW];         // per-cell "has any box" bitmap
    __shared__ float    sred[BLK / 64];

    const int bid = blockIdx.x, tid = threadIdx.x;
    const int img = bid / BLKS_PER_IMG;
    const int rc  = (bid - img * BLKS_PER_IMG) * BLK + tid;   // cell id within image

    // issue coalesced pred loads early (5 float4 per thread, lane-contiguous)
    const float4* src = (const float4*)(pred + (size_t)bid * BLK * 20);
    float4 v0 = src[tid];
    float4 v1 = src[tid + BLK];
    float4 v2 = src[tid + 2 * BLK];
    float4 v3 = src[tid + 3 * BLK];
    float4 v4 = src[tid + 4 * BLK];

    // zero hit bitmap
    if (tid < HITW) s_hit[tid] = 0u;
    if (tid + BLK < HITW) s_hit[tid + BLK] = 0u;   // HITW=392 < 512
    __syncthreads();

    // box table (threads 0..99) — coalesced 500-float read per image
    if (tid < NBOX) {
        const float* t = tgt + ((size_t)img * NBOX + tid) * 5;
        float t0 = t[0], cx = t[1], cy = t[2], w = t[3], h = t[4];
        int cellid = -1; unsigned cb = 0u;
        if (t0 >= 0.f) {
            int cls = min(max((int)t0, 0), 9);
            int col = min(max((int)(cx * (float)S_GRID), 0), S_GRID - 1);
            int row = min(max((int)(cy * (float)S_GRID), 0), S_GRID - 1);
            cellid = row * S_GRID + col;
            cb = 1u << cls;
            atomicOr(&s_hit[cellid >> 5], 1u << (cellid & 31));
        }
        s_cell[tid] = cellid;
        s_box[tid]  = make_float4(cx, cy, w, h);
        s_cbit[tid] = cb;
    }

    // scatter staged preds into padded LDS rows
    {
#define WR(k, vv) { int i = tid + (k) * BLK; float* d = &sp[(i / 5) * PSTRIDE + (i % 5) * 4]; \
                    d[0] = vv.x; d[1] = vv.y; d[2] = vv.z; d[3] = vv.w; }
        WR(0, v0) WR(1, v1) WR(2, v2) WR(3, v3) WR(4, v4)
#undef WR
    }
    __syncthreads();

    const float* P = &sp[tid * PSTRIDE];
    float conf0 = P[4], conf1 = P[9];
    float acc;

    bool hit = (s_hit[rc >> 5] >> (rc & 31)) & 1u;
    if (!hit) {
        acc = 0.1f * (conf0 * conf0 + conf1 * conf1);
    } else {
        float colf = (float)(rc % S_GRID);
        float rowf = (float)(rc / S_GRID);

        // scan boxes ascending: strict '>' keeps first achiever of the max
        // == reference's (max best_iou, then smallest flat index) winner.
        unsigned mask = 0u; float bestv = -1.f; int jwin = 0, bj = 0;
        for (int j = 0; j < NBOX; ++j) {
            if (s_cell[j] == rc) {
                mask |= s_cbit[j];
                float4 g = s_box[j];
                float dx0 = (P[0] + colf) * CELLSZ, dy0 = (P[1] + rowf) * CELLSZ;
                float i0 = iou_fn(dx0, dy0, P[2], P[3], g.x, g.y, g.z, g.w);
                float dx1 = (P[5] + colf) * CELLSZ, dy1 = (P[6] + rowf) * CELLSZ;
                float i1 = iou_fn(dx1, dy1, P[7], P[8], g.x, g.y, g.z, g.w);
                float b = fmaxf(i0, i1);
                if (b > bestv) { bestv = b; jwin = j; bj = (i0 >= i1) ? 0 : 1; }
            }
        }

        float4 g = s_box[jwin];
        float best_iou = bestv;

        float rx = bj ? P[5] : P[0];
        float ry = bj ? P[6] : P[1];
        float rw = bj ? P[7] : P[2];
        float rh = bj ? P[8] : P[3];
        float rconf = bj ? conf1 : conf0;
        float oconf = bj ? conf0 : conf1;

        float pax = (rx + colf) * CELLSZ, pay = (ry + rowf) * CELLSZ;
        float paw = fabsf(rw), pah = fabsf(rh);
        // mirror reference fp order: cx_rel = cx*S - col; gax = (cx_rel+col)/S
        float cx_rel = g.x * (float)S_GRID - colf;
        float cy_rel = g.y * (float)S_GRID - rowf;
        float gax = (cx_rel + colf) * CELLSZ;
        float gay = (cy_rel + rowf) * CELLSZ;
        float lcoord = ciou_fn(pax, pay, paw, pah, gax, gay, g.z, g.w);

        float dobj = rconf - best_iou;

        float lcls = 0.f;
#pragma unroll
        for (int k = 0; k < 10; ++k) {
            float tk = (mask >> k) & 1u ? 1.f : 0.f;
            lcls += focal_fn(P[10 + k], tk);
        }

        acc = 5.f * lcoord + dobj * dobj + 0.1f * (oconf * oconf) + lcls;
    }

    // deterministic block reduction
    for (int off = 32; off > 0; off >>= 1) acc += __shfl_down(acc, off);
    int lane = tid & 63, wid = tid >> 6;
    if (lane == 0) sred[wid] = acc;
    __syncthreads();
    if (tid == 0) {
        float s = 0.f;
#pragma unroll
        for (int w = 0; w < BLK / 64; ++w) s += sred[w];
        partial[bid] = s;
    }
}

// ---------- kernel 2: final reduction ----------

__global__ void reduce_kernel(const float* __restrict__ partial, float* __restrict__ out) {
    float acc = 0.f;
    for (int i = threadIdx.x; i < NBLK; i += blockDim.x) acc += partial[i];
    for (int off = 32; off > 0; off >>= 1) acc += __shfl_down(acc, off);
    __shared__ float sred[BLK / 64];
    int lane = threadIdx.x & 63, wid = threadIdx.x >> 6;
    if (lane == 0) sred[wid] = acc;
    __syncthreads();
    if (threadIdx.x == 0) {
        float s = 0.f;
#pragma unroll
        for (int w = 0; w < BLK / 64; ++w) s += sred[w];
        out[0] = s / (float)BATCH_N;
    }
}

// ---------- launcher: 2 launches, no workspace init needed ----------

extern "C" void kernel_launch(void* const* d_in, const int* in_sizes, int n_in,
                              void* d_out, int out_size, void* d_ws, size_t ws_size,
                              hipStream_t stream) {
    const float* pred = (const float*)d_in[0];
    const float* tgt  = (const float*)d_in[1];
    float* partial = (float*)d_ws;   // 4B * NBLK, fully overwritten every launch

    loss_kernel<<<NBLK, BLK, 0, stream>>>(pred, tgt, partial);
    reduce_kernel<<<1, BLK, 0, stream>>>(partial, (float*)d_out);
}